// Round 4
// baseline (518.326 us; speedup 1.0000x reference)
//
#include <hip/hip_runtime.h>
#include <hip/hip_bf16.h>

#define B_ 4
#define D_ 64
#define N_ 16
#define HW_ 4096

#define LDSA 72
#define LDSB 66

// workspace offsets (bytes)
#define OFF_D2    0u
#define OFF_ATAB  8192u
#define OFF_MEAN  12288u
#define OFF_RSTD  12352u
#define OFF_W9    16384u
#define OFF_UNT   131072u
#define OFF_DELTA 2228224u
#define OFF_BVAL  6422528u
#define OFF_CVAL  7471104u
#define OFF_PART  8519680u

typedef __bf16 v8bf __attribute__((ext_vector_type(8)));
typedef float  v4f  __attribute__((ext_vector_type(4)));

__device__ __forceinline__ unsigned short f2bf(float f){
  __hip_bfloat16 h = __float2bfloat16(f);
  return *reinterpret_cast<unsigned short*>(&h);
}
__device__ __forceinline__ v8bf ld8bf(const unsigned short* p){
  union{uint4 u; v8bf v;} c; c.u = *(const uint4*)p; return c.v;
}

// ---------------- init: spectral-derivative table + A = -exp(logA) ----------
__global__ void k_init(const float* __restrict__ logA,
                       unsigned short* __restrict__ D2w, float* __restrict__ Atab){
  int g = blockIdx.x*256 + threadIdx.x;
  if(g < 4096){
    int r = g>>6, m = g&63;
    int p = (r - m) & 63;
    float s = 0.f;
    for(int k=1;k<32;k++) s += (float)k * sinf(0.09817477042468103f * (float)(k*p));
    D2w[g] = f2bf(-0.0030679615757712823f * s);
  } else if(g < 5120){
    int idx = g - 4096;
    Atab[idx] = -__expf(logA[idx]);
  }
}

// ---------------- repack conv weights to [tap][co(96)][ci(64)] bf16 ---------
__global__ void k_wrepack(const float* __restrict__ wd,
                          const float* __restrict__ wB,
                          const float* __restrict__ wC,
                          unsigned short* __restrict__ W9){
  int idx = blockIdx.x*256 + threadIdx.x;   // 0..6143
  if(idx >= 96*64) return;
  int co = idx>>6, ci = idx&63;
  const float* src;
  if(co < 64)      src = wd + ((size_t)co*64 + ci)*9;
  else if(co < 80) src = wB + ((size_t)(co-64)*64 + ci)*9;
  else             src = wC + ((size_t)(co-80)*64 + ci)*9;
  for(int tap=0; tap<9; tap++)
    W9[((size_t)tap*96 + co)*64 + ci] = f2bf(src[tap]);
}

// ---------------- GroupNorm statistics, stage 1: 1024 partial blocks --------
__global__ void k_gn1(const float* __restrict__ u, float* __restrict__ part){
  int bid = blockIdx.x;                      // bg*64 + sub
  const float* base = u + (size_t)(bid>>6)*65536 + (size_t)(bid&63)*1024;
  int t = threadIdx.x;                       // 0..255
  float4 v = ((const float4*)base)[t];
  float s  = v.x+v.y+v.z+v.w;
  float s2 = v.x*v.x+v.y*v.y+v.z*v.z+v.w*v.w;
  #pragma unroll
  for(int o=32;o>0;o>>=1){ s += __shfl_down(s,o); s2 += __shfl_down(s2,o); }
  __shared__ float ls[4], ls2[4];
  int wv = t>>6;
  if((t&63)==0){ ls[wv]=s; ls2[wv]=s2; }
  __syncthreads();
  if(t==0){
    part[bid]        = ls[0]+ls[1]+ls[2]+ls[3];
    part[1024 + bid] = ls2[0]+ls2[1]+ls2[2]+ls2[3];
  }
}

// ---------------- GroupNorm statistics, stage 2: finalize 16 groups ---------
__global__ void k_gn2(const float* __restrict__ part,
                      float* __restrict__ meanw, float* __restrict__ rstdw){
  int t = threadIdx.x;          // 0..255
  int g = t>>4, i = t&15;       // 16 groups x 16 lanes
  float S=0.f, S2=0.f;
  #pragma unroll
  for(int j=0;j<4;j++){
    S  += part[g*64 + i*4 + j];
    S2 += part[1024 + g*64 + i*4 + j];
  }
  #pragma unroll
  for(int o=8;o>0;o>>=1){ S += __shfl_down(S,o,16); S2 += __shfl_down(S2,o,16); }
  if(i==0){
    float mu = S/65536.f;
    float var = S2/65536.f - mu*mu;
    meanw[g]=mu; rstdw[g]=rsqrtf(var+1e-5f);
  }
}

// ---------------- apply GN + transpose to unT[b][pixel][ci] (bf16) ----------
__global__ __launch_bounds__(512) void k_unT(
    const float* __restrict__ u_t,
    const float* __restrict__ meanw, const float* __restrict__ rstdw,
    const float* __restrict__ gamma, const float* __restrict__ beta,
    unsigned short* __restrict__ unT){
  __shared__ unsigned short T[64*LDSA];
  int bid = blockIdx.x;
  int b = bid>>6, h = bid&63;
  int t = threadIdx.x;                 // 0..511
  int w = t&63, cg = t>>6;             // cg = wave 0..7
  #pragma unroll
  for(int i=0;i<8;i++){
    int c = cg*8 + i;
    float x = u_t[(((size_t)b*64 + c)*64 + h)*64 + w];
    int g = c>>4;
    float v = (x - meanw[b*4+g])*rstdw[b*4+g]*gamma[c] + beta[c];
    T[w*LDSA + c] = f2bf(v);
  }
  __syncthreads();
  int w2 = t>>3, cq = t&7;             // 64 pixels x 8 ci-octets
  uint4 v0 = *(uint4*)&T[w2*LDSA + cq*8];
  uint4* dst = (uint4*)(unT + ((size_t)b*HW_ + h*64 + w2)*64 + cq*8);
  dst[0] = v0;
}

// ---------------- conv as 9 shifted GEMMs via MFMA (6-way co split) ---------
__global__ __launch_bounds__(256) void k_conv(
    const unsigned short* __restrict__ unT,
    const unsigned short* __restrict__ W9,
    const float* __restrict__ b_d,
    const float* __restrict__ dtp,
    float* __restrict__ deltaw, float* __restrict__ Bvalw, float* __restrict__ Cvalw){
  int bid = blockIdx.x;
  int cg = bid >> 8;                   // 0..5  (co group of 16)
  int b = (bid>>6) & 3, h = bid & 63;
  int t = threadIdx.x;
  int wv = t>>6, l = t&63;
  int lr = l&15, lk = l>>4;
  v4f acc = (v4f){0.f,0.f,0.f,0.f};
  int wpix = wv*16 + lr;
  #pragma unroll
  for(int tap=0; tap<9; tap++){
    int dy = tap/3 - 1, dx = tap - (tap/3)*3 - 1;
    int hh = (h+dy)&63;
    int ww = (wpix+dx)&63;
    const unsigned short* bp = unT + ((size_t)b*HW_ + hh*64 + ww)*64;
    const unsigned short* ap = W9 + ((size_t)tap*96 + cg*16)*64;
    #pragma unroll
    for(int ks=0; ks<2; ks++){
      int k0 = ks*32 + lk*8;
      v8bf bfrag = ld8bf(bp + k0);
      v8bf afrag = ld8bf(ap + lr*64 + k0);
      acc = __builtin_amdgcn_mfma_f32_16x16x32_bf16(afrag, bfrag, acc, 0,0,0);
    }
  }
  float dt = dtp[0];
  int p = h*64 + wpix;
  #pragma unroll
  for(int r=0;r<4;r++){
    int co = cg*16 + lk*4 + r;
    float v = acc[r];
    if(cg < 4){
      float x = v + b_d[co] + dt;
      float sp = (x > 15.f) ? x : log1pf(__expf(x));
      sp = fminf(fmaxf(sp, 1e-4f), 5.f);
      deltaw[((size_t)b*64 + co)*HW_ + p] = sp;
    } else if(cg == 4){
      Bvalw[((size_t)b*16 + (co-64))*HW_ + p] = v;
    } else {
      Cvalw[((size_t)b*16 + (co-80))*HW_ + p] = v;
    }
  }
}

// ---------------- fused spectral-grad + state update ------------------------
// One (b,d,nq) per block, 4 sequential n with DOUBLE-BUFFERED LDS:
// prefetch m0[n+1] (global->regs) is issued BEFORE the compute phase of n and
// written to LDS[next] AFTER it -> HBM latency hides under MFMA+epilogue.
// u/delta loaded once per block into registers (4x fewer reads of those
// planes than the 1-n-per-block variant). D2 fragments from global (L2).
// LDS 2x17.7KB -> 4 blocks/CU, 16 waves/CU.
__global__ __launch_bounds__(256,4) void k_main(
    const float* __restrict__ u_t,
    const float* __restrict__ s_prev,
    const unsigned short* __restrict__ D2w,
    const float* __restrict__ Atab,
    const float* __restrict__ deltaw,
    const float* __restrict__ Bvalw,
    float* __restrict__ out_s){
  __shared__ unsigned short Ms72[2][64*LDSA];
  __shared__ unsigned short MsT [2][64*LDSB];

  // bijective XCD swizzle (1024 % 8 == 0): the 4 nq-blocks of one (b,d)
  // land on the same XCD -> shared delta/u/B stay L2-local.
  int bid = blockIdx.x;
  int lid = (bid & 7)*128 + (bid >> 3);
  int nq = lid & 3;
  int d  = (lid>>2) & 63;
  int b  = lid >> 8;
  int t = threadIdx.x;
  int wv = t>>6, l = t&63;
  int lr = l & 15, lk = l >> 4;
  int r0 = wv*16;

  const size_t PL = (size_t)D_*N_*HW_;
  size_t bd = (size_t)b*64 + d;
  size_t sb0 = (size_t)b*3*PL + (size_t)d*(N_*HW_);
  const float* up = u_t + bd*HW_;
  const float* dp = deltaw + bd*HW_;

  // persistent per-thread u and delta in fragment layout (reused for all 4 n)
  float uvals[16], dvals[16];
  int pbase = (r0 + lk*4)*64 + lr;
  #pragma unroll
  for(int ct=0;ct<4;ct++){
    #pragma unroll
    for(int r=0;r<4;r++){
      int p = pbase + r*64 + ct*16;
      uvals[ct*4+r] = up[p];
      dvals[ct*4+r] = dp[p];
    }
  }

  int n0 = nq*4;
  // prologue: stage m0[n0] into buffer 0
  {
    const float* m0p = s_prev + sb0 + (size_t)n0*HW_;
    #pragma unroll
    for(int j=0;j<4;j++){
      int chunk = t + 256*j;           // 0..1023 float4 chunks
      int rrow = chunk>>4, cb = chunk&15;
      float4 v = ((const float4*)m0p)[chunk];
      unsigned short e0=f2bf(v.x), e1=f2bf(v.y), e2=f2bf(v.z), e3=f2bf(v.w);
      unsigned int lo = (unsigned int)e0 | ((unsigned int)e1<<16);
      unsigned int hi = (unsigned int)e2 | ((unsigned int)e3<<16);
      unsigned int* d72 = (unsigned int*)&Ms72[0][rrow*LDSA + cb*4];
      d72[0]=lo; d72[1]=hi;
      int c0 = cb*4;
      MsT[0][(c0  )*LDSB + rrow] = e0;
      MsT[0][(c0+1)*LDSB + rrow] = e1;
      MsT[0][(c0+2)*LDSB + rrow] = e2;
      MsT[0][(c0+3)*LDSB + rrow] = e3;
    }
  }
  __syncthreads();

  for(int ni=0; ni<4; ni++){
    int n = n0 + ni;
    int cur = ni & 1;
    const unsigned short* M72c = Ms72[cur];
    const unsigned short* MsTc = MsT[cur];

    // ---- issue prefetch of m0[n+1] (in flight across the compute phase) ----
    float4 nv[4];
    if(ni < 3){
      const float* mnext = s_prev + sb0 + (size_t)(n+1)*HW_;
      #pragma unroll
      for(int j=0;j<4;j++) nv[j] = ((const float4*)mnext)[t + 256*j];
    }

    float An = Atab[d*16 + n];
    const float* m0p = s_prev + sb0 + (size_t)n*HW_;
    const float* mxp = m0p + PL;
    const float* myp = m0p + 2*PL;
    float* so = out_s + sb0 + (size_t)n*HW_;
    const float* Bp = Bvalw + ((size_t)b*16 + n)*HW_;

    // ---- compute phase ----
    #pragma unroll
    for(int ct=0; ct<4; ct++){
      float m0v[4], mxv[4], myv[4], Bv[4];
      #pragma unroll
      for(int r=0;r<4;r++){
        int p = pbase + r*64 + ct*16;
        m0v[r] = m0p[p];       // L2-hit: staged by this block moments ago
        mxv[r] = mxp[p];
        myv[r] = myp[p];
        Bv[r]  = Bp[p];
      }
      v4f gx = {0.f,0.f,0.f,0.f}, gy = {0.f,0.f,0.f,0.f};
      #pragma unroll
      for(int ks=0; ks<2; ks++){
        int k0 = ks*32 + lk*8;
        // grad_x = M * D2^T : A = M rows (LDS), B[k][j]=D2[j][k] (global/L2)
        v8bf a_gx = ld8bf(&M72c[(r0+lr)*LDSA + k0]);
        v8bf b_gx = ld8bf(D2w + (ct*16+lr)*64 + k0);
        gx = __builtin_amdgcn_mfma_f32_16x16x32_bf16(a_gx, b_gx, gx, 0,0,0);
        // grad_y = D2 * M : A = D2 rows (global/L2), B[k][j]=M[k][j]=MsT[j][k]
        v8bf a_gy = ld8bf(D2w + (r0+lr)*64 + k0);
        v8bf b_gy = ld8bf(&MsTc[(ct*16+lr)*LDSB + k0]);
        gy = __builtin_amdgcn_mfma_f32_16x16x32_bf16(a_gy, b_gy, gy, 0,0,0);
      }
      #pragma unroll
      for(int r=0;r<4;r++){
        int pi = ct*4+r;
        int p = pbase + r*64 + ct*16;
        float dv = dvals[pi];
        float ab = __expf(dv*An);
        float m0n = ab*m0v[r] + dv*Bv[r]*uvals[pi];
        so[p]        = m0n;
        so[PL + p]   = ab*(mxv[r] - gx[r]);
        so[2*PL + p] = ab*(myv[r] - gy[r]);
      }
    }

    // ---- write prefetched m0[n+1] into the other buffer, then barrier ----
    if(ni < 3){
      unsigned short* M72n = Ms72[cur^1];
      unsigned short* MsTn = MsT[cur^1];
      #pragma unroll
      for(int j=0;j<4;j++){
        int chunk = t + 256*j;
        int rrow = chunk>>4, cb = chunk&15;
        float4 v = nv[j];
        unsigned short e0=f2bf(v.x), e1=f2bf(v.y), e2=f2bf(v.z), e3=f2bf(v.w);
        unsigned int lo = (unsigned int)e0 | ((unsigned int)e1<<16);
        unsigned int hi = (unsigned int)e2 | ((unsigned int)e3<<16);
        unsigned int* d72 = (unsigned int*)&M72n[rrow*LDSA + cb*4];
        d72[0]=lo; d72[1]=hi;
        int c0 = cb*4;
        MsTn[(c0  )*LDSB + rrow] = e0;
        MsTn[(c0+1)*LDSB + rrow] = e1;
        MsTn[(c0+2)*LDSB + rrow] = e2;
        MsTn[(c0+3)*LDSB + rrow] = e3;
      }
      __syncthreads();
    }
  }
}

// ---------------- y epilogue: y = sum_n m0_new*C + u*D_param ----------------
__global__ void k_y(const float* __restrict__ m0new,    // = out_s base
                    const float* __restrict__ Cvalw,
                    const float* __restrict__ u_t,
                    const float* __restrict__ Dp,
                    float* __restrict__ out_y){
  int i = blockIdx.x*128 + threadIdx.x;   // 0..262143 float4s
  int b = i>>16;
  int d = (i>>10)&63;
  int pq = i & 1023;
  const size_t PL = (size_t)D_*N_*HW_;
  float Dv = Dp[d];
  const float4* m0b = (const float4*)(m0new + (size_t)b*3*PL + (size_t)d*(N_*HW_)) + pq;
  const float4* Cb  = (const float4*)Cvalw + (size_t)b*16*1024 + pq;
  float4 acc = {0.f,0.f,0.f,0.f};
  #pragma unroll
  for(int n=0;n<16;n++){
    float4 m = m0b[(size_t)n*1024];
    float4 c = Cb[(size_t)n*1024];
    acc.x += m.x*c.x; acc.y += m.y*c.y; acc.z += m.z*c.z; acc.w += m.w*c.w;
  }
  float4 uv = ((const float4*)u_t)[i];
  float4 o;
  o.x = acc.x + uv.x*Dv;
  o.y = acc.y + uv.y*Dv;
  o.z = acc.z + uv.z*Dv;
  o.w = acc.w + uv.w*Dv;
  ((float4*)out_y)[i] = o;
}

extern "C" void kernel_launch(void* const* d_in, const int* in_sizes, int n_in,
                              void* d_out, int out_size, void* d_ws, size_t ws_size,
                              hipStream_t stream){
  const float* u_t    = (const float*)d_in[0];
  const float* s_prev = (const float*)d_in[1];
  const float* gamma  = (const float*)d_in[2];
  const float* beta   = (const float*)d_in[3];
  const float* w_d    = (const float*)d_in[4];
  const float* b_d    = (const float*)d_in[5];
  const float* w_B    = (const float*)d_in[6];
  const float* w_C    = (const float*)d_in[7];
  const float* logA   = (const float*)d_in[8];
  const float* Dp     = (const float*)d_in[9];
  const float* dtp    = (const float*)d_in[10];

  char* ws = (char*)d_ws;
  unsigned short* D2w  = (unsigned short*)(ws + OFF_D2);
  float* Atab          = (float*)(ws + OFF_ATAB);
  float* meanw         = (float*)(ws + OFF_MEAN);
  float* rstdw         = (float*)(ws + OFF_RSTD);
  unsigned short* W9   = (unsigned short*)(ws + OFF_W9);
  unsigned short* unT  = (unsigned short*)(ws + OFF_UNT);
  float* deltaw        = (float*)(ws + OFF_DELTA);
  float* Bvalw         = (float*)(ws + OFF_BVAL);
  float* Cvalw         = (float*)(ws + OFF_CVAL);
  float* part          = (float*)(ws + OFF_PART);

  float* out_y = (float*)d_out;
  float* out_s = out_y + 1048576;

  k_init   <<<20, 256, 0, stream>>>(logA, D2w, Atab);
  k_wrepack<<<24, 256, 0, stream>>>(w_d, w_B, w_C, W9);
  k_gn1    <<<1024, 256, 0, stream>>>(u_t, part);
  k_gn2    <<<1, 256, 0, stream>>>(part, meanw, rstdw);
  k_unT    <<<256, 512, 0, stream>>>(u_t, meanw, rstdw, gamma, beta, unT);
  k_conv   <<<1536, 256, 0, stream>>>(unT, W9, b_d, dtp, deltaw, Bvalw, Cvalw);
  k_main   <<<1024, 256, 0, stream>>>(u_t, s_prev, D2w, Atab, deltaw, Bvalw, out_s);
  k_y      <<<2048, 128, 0, stream>>>(out_s, Cvalw, u_t, Dp, out_y);
}

// Round 5
// 441.418 us; speedup vs baseline: 1.1742x; 1.1742x over previous
//
#include <hip/hip_runtime.h>
#include <hip/hip_bf16.h>

#define B_ 4
#define D_ 64
#define N_ 16
#define HW_ 4096

#define LDSA 72
#define LDSB 66

// workspace offsets (bytes)
#define OFF_D2    0u
#define OFF_ATAB  8192u
#define OFF_W9    16384u
#define OFF_UNT   131072u
#define OFF_DELTA 2228224u
#define OFF_BVAL  6422528u
#define OFF_CVAL  7471104u
#define OFF_PART  8519680u

typedef __bf16 v8bf __attribute__((ext_vector_type(8)));
typedef float  v4f  __attribute__((ext_vector_type(4)));

__device__ __forceinline__ unsigned short f2bf(float f){
  __hip_bfloat16 h = __float2bfloat16(f);
  return *reinterpret_cast<unsigned short*>(&h);
}
__device__ __forceinline__ v8bf ld8bf(const unsigned short* p){
  union{uint4 u; v8bf v;} c; c.u = *(const uint4*)p; return c.v;
}

// ---------------- prep: D2 table + Atab + conv-weight repack (merged) -------
__global__ void k_prep(const float* __restrict__ logA,
                       const float* __restrict__ wd,
                       const float* __restrict__ wB,
                       const float* __restrict__ wC,
                       unsigned short* __restrict__ D2w,
                       float* __restrict__ Atab,
                       unsigned short* __restrict__ W9){
  int blk = blockIdx.x;
  if(blk < 20){
    int g = blk*256 + threadIdx.x;
    if(g < 4096){
      int r = g>>6, m = g&63;
      int p = (r - m) & 63;
      float s = 0.f;
      for(int k=1;k<32;k++) s += (float)k * sinf(0.09817477042468103f * (float)(k*p));
      D2w[g] = f2bf(-0.0030679615757712823f * s);
    } else if(g < 5120){
      int idx = g - 4096;
      Atab[idx] = -__expf(logA[idx]);
    }
  } else {
    int idx = (blk-20)*256 + threadIdx.x;   // 0..6143
    if(idx >= 96*64) return;
    int co = idx>>6, ci = idx&63;
    const float* src;
    if(co < 64)      src = wd + ((size_t)co*64 + ci)*9;
    else if(co < 80) src = wB + ((size_t)(co-64)*64 + ci)*9;
    else             src = wC + ((size_t)(co-80)*64 + ci)*9;
    for(int tap=0; tap<9; tap++)
      W9[((size_t)tap*96 + co)*64 + ci] = f2bf(src[tap]);
  }
}

// ---------------- GroupNorm statistics, stage 1: 1024 partial blocks --------
__global__ void k_gn1(const float* __restrict__ u, float* __restrict__ part){
  int bid = blockIdx.x;                      // bg*64 + sub
  const float* base = u + (size_t)(bid>>6)*65536 + (size_t)(bid&63)*1024;
  int t = threadIdx.x;                       // 0..255
  float4 v = ((const float4*)base)[t];
  float s  = v.x+v.y+v.z+v.w;
  float s2 = v.x*v.x+v.y*v.y+v.z*v.z+v.w*v.w;
  #pragma unroll
  for(int o=32;o>0;o>>=1){ s += __shfl_down(s,o); s2 += __shfl_down(s2,o); }
  __shared__ float ls[4], ls2[4];
  int wv = t>>6;
  if((t&63)==0){ ls[wv]=s; ls2[wv]=s2; }
  __syncthreads();
  if(t==0){
    part[bid]        = ls[0]+ls[1]+ls[2]+ls[3];
    part[1024 + bid] = ls2[0]+ls2[1]+ls2[2]+ls2[3];
  }
}

// ---------------- GN finalize (folded) + apply + transpose ------------------
__global__ __launch_bounds__(512) void k_unT(
    const float* __restrict__ u_t,
    const float* __restrict__ part,
    const float* __restrict__ gamma, const float* __restrict__ beta,
    unsigned short* __restrict__ unT){
  __shared__ unsigned short T[64*LDSA];
  __shared__ float smean[16], srstd[16];
  int bid = blockIdx.x;
  int b = bid>>6, h = bid&63;
  int t = threadIdx.x;                 // 0..511
  // redundant per-block GN finalize (2 KB of L2-hot partials)
  if(t < 256){
    int g = t>>4, i = t&15;
    float S=0.f, S2=0.f;
    #pragma unroll
    for(int j=0;j<4;j++){
      S  += part[g*64 + i*4 + j];
      S2 += part[1024 + g*64 + i*4 + j];
    }
    #pragma unroll
    for(int o=8;o>0;o>>=1){ S += __shfl_down(S,o,16); S2 += __shfl_down(S2,o,16); }
    if(i==0){
      float mu = S/65536.f;
      float var = S2/65536.f - mu*mu;
      smean[g]=mu; srstd[g]=rsqrtf(var+1e-5f);
    }
  }
  __syncthreads();
  int w = t&63, cg = t>>6;             // cg = wave 0..7
  #pragma unroll
  for(int i=0;i<8;i++){
    int c = cg*8 + i;
    float x = u_t[(((size_t)b*64 + c)*64 + h)*64 + w];
    int g = c>>4;
    float v = (x - smean[b*4+g])*srstd[b*4+g]*gamma[c] + beta[c];
    T[w*LDSA + c] = f2bf(v);
  }
  __syncthreads();
  int w2 = t>>3, cq = t&7;             // 64 pixels x 8 ci-octets
  uint4 v0 = *(uint4*)&T[w2*LDSA + cq*8];
  uint4* dst = (uint4*)(unT + ((size_t)b*HW_ + h*64 + w2)*64 + cq*8);
  dst[0] = v0;
}

// ---------------- conv as 9 shifted GEMMs via MFMA (6-way co split) ---------
__global__ __launch_bounds__(256) void k_conv(
    const unsigned short* __restrict__ unT,
    const unsigned short* __restrict__ W9,
    const float* __restrict__ b_d,
    const float* __restrict__ dtp,
    float* __restrict__ deltaw, float* __restrict__ Bvalw, float* __restrict__ Cvalw){
  int bid = blockIdx.x;
  int cg = bid >> 8;                   // 0..5  (co group of 16)
  int b = (bid>>6) & 3, h = bid & 63;
  int t = threadIdx.x;
  int wv = t>>6, l = t&63;
  int lr = l&15, lk = l>>4;
  v4f acc = (v4f){0.f,0.f,0.f,0.f};
  int wpix = wv*16 + lr;
  #pragma unroll
  for(int tap=0; tap<9; tap++){
    int dy = tap/3 - 1, dx = tap - (tap/3)*3 - 1;
    int hh = (h+dy)&63;
    int ww = (wpix+dx)&63;
    const unsigned short* bp = unT + ((size_t)b*HW_ + hh*64 + ww)*64;
    const unsigned short* ap = W9 + ((size_t)tap*96 + cg*16)*64;
    #pragma unroll
    for(int ks=0; ks<2; ks++){
      int k0 = ks*32 + lk*8;
      v8bf bfrag = ld8bf(bp + k0);
      v8bf afrag = ld8bf(ap + lr*64 + k0);
      acc = __builtin_amdgcn_mfma_f32_16x16x32_bf16(afrag, bfrag, acc, 0,0,0);
    }
  }
  float dt = dtp[0];
  int p = h*64 + wpix;
  #pragma unroll
  for(int r=0;r<4;r++){
    int co = cg*16 + lk*4 + r;
    float v = acc[r];
    if(cg < 4){
      float x = v + b_d[co] + dt;
      float sp = (x > 15.f) ? x : log1pf(__expf(x));
      sp = fminf(fmaxf(sp, 1e-4f), 5.f);
      deltaw[((size_t)b*64 + co)*HW_ + p] = sp;
    } else if(cg == 4){
      Bvalw[((size_t)b*16 + (co-64))*HW_ + p] = v;
    } else {
      Cvalw[((size_t)b*16 + (co-80))*HW_ + p] = v;
    }
  }
}

// ---------------- spectral gradients: one (b,d,n) plane per block -----------
// Writes gx into out_s's mx-plane region and gy into the my-plane region
// (fp32 scratch, overwritten in-place by k_update). Write-only epilogue.
__global__ __launch_bounds__(256) void k_grad(
    const float* __restrict__ s_prev,
    const unsigned short* __restrict__ D2w,
    float* __restrict__ out_s){
  __shared__ unsigned short Ms72[64*LDSA];
  __shared__ unsigned short MsT [64*LDSB];
  int bid = blockIdx.x;                // (b*64+d)*16 + n
  int n = bid & 15;
  int d = (bid>>4) & 63;
  int b = bid >> 10;
  int t = threadIdx.x;
  int wv = t>>6, l = t&63;
  int lr = l&15, lk = l>>4;
  int r0 = wv*16;

  const size_t PL = (size_t)D_*N_*HW_;
  size_t plane = (size_t)d*(N_*HW_) + (size_t)n*HW_;
  const float* m0p = s_prev + (size_t)b*3*PL + plane;
  float* gxp = out_s + (size_t)b*3*PL + PL   + plane;
  float* gyp = out_s + (size_t)b*3*PL + 2*PL + plane;

  // stage m0 (fp32 -> bf16) into row-major AND transposed LDS layouts
  #pragma unroll
  for(int j=0;j<4;j++){
    int chunk = t + 256*j;             // 0..1023 float4 chunks
    int rrow = chunk>>4, cb = chunk&15;
    float4 v = ((const float4*)m0p)[chunk];
    unsigned short e0=f2bf(v.x), e1=f2bf(v.y), e2=f2bf(v.z), e3=f2bf(v.w);
    unsigned int lo = (unsigned int)e0 | ((unsigned int)e1<<16);
    unsigned int hi = (unsigned int)e2 | ((unsigned int)e3<<16);
    unsigned int* d72 = (unsigned int*)&Ms72[rrow*LDSA + cb*4];
    d72[0]=lo; d72[1]=hi;
    int c0 = cb*4;
    MsT[(c0  )*LDSB + rrow] = e0;
    MsT[(c0+1)*LDSB + rrow] = e1;
    MsT[(c0+2)*LDSB + rrow] = e2;
    MsT[(c0+3)*LDSB + rrow] = e3;
  }
  __syncthreads();

  #pragma unroll
  for(int ct=0; ct<4; ct++){
    v4f gx = {0.f,0.f,0.f,0.f}, gy = {0.f,0.f,0.f,0.f};
    #pragma unroll
    for(int ks=0; ks<2; ks++){
      int k0 = ks*32 + lk*8;
      // grad_x = M * D2^T : A = M rows (LDS), B[k][j]=D2[j][k] (global/L2)
      v8bf a_gx = ld8bf(&Ms72[(r0+lr)*LDSA + k0]);
      v8bf b_gx = ld8bf(D2w + (ct*16+lr)*64 + k0);
      gx = __builtin_amdgcn_mfma_f32_16x16x32_bf16(a_gx, b_gx, gx, 0,0,0);
      // grad_y = D2 * M : A = D2 rows (global/L2), B[k][j]=M[k][j]=MsT[j][k]
      v8bf a_gy = ld8bf(D2w + (r0+lr)*64 + k0);
      v8bf b_gy = ld8bf(&MsT[(ct*16+lr)*LDSB + k0]);
      gy = __builtin_amdgcn_mfma_f32_16x16x32_bf16(a_gy, b_gy, gy, 0,0,0);
    }
    #pragma unroll
    for(int r=0;r<4;r++){
      int p = (r0 + lk*4 + r)*64 + ct*16 + lr;
      gxp[p] = gx[r];
      gyp[p] = gy[r];
    }
  }
}

// ---------------- state update + fused y: pure linear streaming -------------
// One (b,d,chunk-of-1024px) per block; loop n=0..15; every access is a
// coalesced float4. gx/gy are read from the out_s mx/my regions and
// overwritten in-place (same thread, same address). y accumulated in regs.
__global__ __launch_bounds__(256) void k_update(
    const float* __restrict__ u_t,
    const float* __restrict__ s_prev,
    const float* __restrict__ Atab,
    const float* __restrict__ deltaw,
    const float* __restrict__ Bvalw,
    const float* __restrict__ Cvalw,
    const float* __restrict__ Dp,
    float* __restrict__ out_y,
    float* __restrict__ out_s){
  int bid = blockIdx.x;                // (b*64+d)*4 + ch
  int ch = bid & 3;
  int d  = (bid>>2) & 63;
  int b  = bid >> 8;
  int t = threadIdx.x;
  int q = ch*256 + t;                  // float4 index in a 4096-px plane

  const size_t PL = (size_t)D_*N_*HW_;
  size_t bd = (size_t)b*64 + d;
  size_t sb = (size_t)b*3*PL + (size_t)d*(N_*HW_);

  v4f dv = ((const v4f*)(deltaw + bd*HW_))[q];
  v4f uv = ((const v4f*)(u_t    + bd*HW_))[q];
  v4f yacc = {0.f,0.f,0.f,0.f};

  #pragma unroll 4
  for(int n=0; n<16; n++){
    size_t off = sb + (size_t)n*HW_;
    v4f m0 = ((const v4f*)(s_prev + off       ))[q];
    v4f mx = ((const v4f*)(s_prev + off + PL  ))[q];
    v4f my = ((const v4f*)(s_prev + off + 2*PL))[q];
    v4f gx = ((const v4f*)(out_s  + off + PL  ))[q];
    v4f gy = ((const v4f*)(out_s  + off + 2*PL))[q];
    v4f Bv = ((const v4f*)(Bvalw + ((size_t)b*16+n)*HW_))[q];
    v4f Cv = ((const v4f*)(Cvalw + ((size_t)b*16+n)*HW_))[q];
    float An = Atab[d*16 + n];
    v4f ab;
    #pragma unroll
    for(int r=0;r<4;r++) ab[r] = __expf(dv[r]*An);
    v4f m0n = ab*m0 + dv*Bv*uv;
    v4f mxn = ab*(mx - gx);
    v4f myn = ab*(my - gy);
    ((v4f*)(out_s + off       ))[q] = m0n;
    ((v4f*)(out_s + off + PL  ))[q] = mxn;
    ((v4f*)(out_s + off + 2*PL))[q] = myn;
    yacc += m0n*Cv;
  }
  float Dv = Dp[d];
  v4f o = yacc + uv*Dv;
  ((v4f*)(out_y + bd*HW_))[q] = o;
}

extern "C" void kernel_launch(void* const* d_in, const int* in_sizes, int n_in,
                              void* d_out, int out_size, void* d_ws, size_t ws_size,
                              hipStream_t stream){
  const float* u_t    = (const float*)d_in[0];
  const float* s_prev = (const float*)d_in[1];
  const float* gamma  = (const float*)d_in[2];
  const float* beta   = (const float*)d_in[3];
  const float* w_d    = (const float*)d_in[4];
  const float* b_d    = (const float*)d_in[5];
  const float* w_B    = (const float*)d_in[6];
  const float* w_C    = (const float*)d_in[7];
  const float* logA   = (const float*)d_in[8];
  const float* Dp     = (const float*)d_in[9];
  const float* dtp    = (const float*)d_in[10];

  char* ws = (char*)d_ws;
  unsigned short* D2w  = (unsigned short*)(ws + OFF_D2);
  float* Atab          = (float*)(ws + OFF_ATAB);
  unsigned short* W9   = (unsigned short*)(ws + OFF_W9);
  unsigned short* unT  = (unsigned short*)(ws + OFF_UNT);
  float* deltaw        = (float*)(ws + OFF_DELTA);
  float* Bvalw         = (float*)(ws + OFF_BVAL);
  float* Cvalw         = (float*)(ws + OFF_CVAL);
  float* part          = (float*)(ws + OFF_PART);

  float* out_y = (float*)d_out;
  float* out_s = out_y + 1048576;

  k_prep  <<<44, 256, 0, stream>>>(logA, w_d, w_B, w_C, D2w, Atab, W9);
  k_gn1   <<<1024, 256, 0, stream>>>(u_t, part);
  k_grad  <<<4096, 256, 0, stream>>>(s_prev, D2w, out_s);
  k_unT   <<<256, 512, 0, stream>>>(u_t, part, gamma, beta, unT);
  k_conv  <<<1536, 256, 0, stream>>>(unT, W9, b_d, dtp, deltaw, Bvalw, Cvalw);
  k_update<<<1024, 256, 0, stream>>>(u_t, s_prev, Atab, deltaw, Bvalw, Cvalw, Dp, out_y, out_s);
}